// Round 7
// baseline (138.333 us; speedup 1.0000x reference)
//
#include <hip/hip_runtime.h>
#include <hip/hip_bf16.h>
#include <stdint.h>
#include <math.h>

typedef __attribute__((ext_vector_type(8))) short bf16x8;
typedef __attribute__((ext_vector_type(4))) float f32x4;

#define TSEQ 4096
#define LOG2E 1.44269504088896340736f
#define SLOPE 0.70710678118654752440f
#define SL2E (SLOPE * LOG2E)

__device__ __forceinline__ unsigned short f32_to_bf16(float f) {
  union { float f; unsigned int u; } v; v.f = f;
  unsigned int r = v.u + 0x7fffu + ((v.u >> 16) & 1u);
  return (unsigned short)(r >> 16);
}

__device__ __forceinline__ unsigned int pk2(float a, float b) {
  union { __hip_bfloat162 h; unsigned int u; } c;
  c.h = __float22bfloat162_rn(make_float2(a, b));  // v_cvt_pk_bf16_f32
  return c.u;
}
__device__ __forceinline__ bf16x8 cvt8(f32x4 a, f32x4 b) {
  union { unsigned int u[4]; bf16x8 v; } r;
  r.u[0] = pk2(a[0], a[1]); r.u[1] = pk2(a[2], a[3]);
  r.u[2] = pk2(b[0], b[1]); r.u[3] = pk2(b[2], b[3]);
  return r.v;
}

// async global->LDS, 16B/lane; dest = wave-uniform base + lane*16 (verified R3/R6)
__device__ __forceinline__ void async_cp16(const void* g, void* l) {
  __builtin_amdgcn_global_load_lds(
      (const __attribute__((address_space(1))) unsigned int*)g,
      (__attribute__((address_space(3))) unsigned int*)l, 16, 0, 0);
}

// ---- kernel 1: W fp32 -> FRAGMENT-MAJOR bf16 (q pre-scaled 1/32) + vt ones ----
// Wb frag(ci,s,lane)[j] = W[n=(ci&3)*16+(lane&15)][k=s*32+(lane>>4)*8+j],
// ci = coltile 0..11 (q:0-3,k:4-7,v:8-11), at offset ((ci*32+s)*64+lane)*8.
__global__ __launch_bounds__(256) void init_kernel(
    const float* __restrict__ wq, const float* __restrict__ wk,
    const float* __restrict__ wv, unsigned short* __restrict__ Wb,
    unsigned short* __restrict__ vt) {
  int tid = blockIdx.x * 256 + threadIdx.x;  // 0..131071
  if (tid < 24576) {
    int lane = tid & 63, s = (tid >> 6) & 31, nt = (tid >> 11) & 3, t = tid >> 13;
    int n = nt * 16 + (lane & 15);
    int k = s * 32 + (lane >> 4) * 8;
    const float* src = (t == 0 ? wq : (t == 1 ? wk : wv)) + (size_t)n * 1024 + k;
    f32x4 a = *(const f32x4*)src;
    f32x4 b = *(const f32x4*)(src + 4);
    if (t == 0) {
#pragma unroll
      for (int j = 0; j < 4; ++j) { a[j] *= 0.03125f; b[j] *= 0.03125f; }
    }
    *(bf16x8*)(Wb + (size_t)tid * 8) = cvt8(a, b);
  }
  // vt ones rows (dims 64..79), vt layout [4][80][4096]
  int b2 = tid >> 15, off = (tid & 32767) * 2;
  *(unsigned int*)(vt + (size_t)b2 * 327680 + 262144 + off) = 0x3F803F80u;
}

// ---- kernel 2: qkv projection -------------------------------------------------
// 512 blocks x 256 thr; block = 32 rows x 192 cols; 8 steps of K=128.
// Per step: x -> registers (issued BEFORE barrier; compiler can't sink loads
// across __syncthreads, and the barrier's vmcnt(0) drains them with the W DMA
// -> one concurrent latency per step, not 16 serial ones). W -> LDS via
// global_load_lds, frag-major. 48 KB LDS -> 3 blocks/CU overlap the drains.
__global__ __launch_bounds__(256, 3) void proj_kernel(
    const float* __restrict__ x, const unsigned short* __restrict__ Wb,
    unsigned short* __restrict__ qb, unsigned short* __restrict__ kb,
    unsigned short* __restrict__ vt) {
  __shared__ unsigned short wbuf[12][4][64][8];  // 48 KB, frag-major

  const int lane = threadIdx.x & 63;
  const int wave = threadIdx.x >> 6;
  const int l16 = lane & 15, quad = lane >> 4;
  const int R0 = blockIdx.x * 32;
  const int ci0 = wave * 3;

  f32x4 acc[2][3];
#pragma unroll
  for (int st = 0; st < 2; ++st)
#pragma unroll
    for (int j = 0; j < 3; ++j) acc[st][j] = (f32x4){0.f, 0.f, 0.f, 0.f};

  const float* xb0 = x + (size_t)(R0 + l16) * 1024 + quad * 8;
  const float* xb1 = xb0 + 16 * 1024;
  const unsigned short* wsrc0 = Wb + ((size_t)(ci0 * 32) * 64 + lane) * 8;

#pragma unroll 1
  for (int step = 0; step < 8; ++step) {
    // x loads: 16 x 16B per lane-pair of rowtiles, all in flight at the barrier
    f32x4 xr[2][4][2];
#pragma unroll
    for (int ss = 0; ss < 4; ++ss) {
#pragma unroll
      for (int p = 0; p < 2; ++p) {
        xr[0][ss][p] = *(const f32x4*)(xb0 + step * 128 + ss * 32 + p * 4);
        xr[1][ss][p] = *(const f32x4*)(xb1 + step * 128 + ss * 32 + p * 4);
      }
    }
    // W DMA: 12 lane-contiguous 1KB copies per wave
#pragma unroll
    for (int j = 0; j < 3; ++j)
#pragma unroll
      for (int ss = 0; ss < 4; ++ss)
        async_cp16(wsrc0 + ((size_t)(j * 32 + step * 4 + ss) * 64) * 8,
                   &wbuf[ci0 + j][ss][0][0]);
    __syncthreads();  // drains x loads + W DMA together (one latency)

#pragma unroll
    for (int ss = 0; ss < 4; ++ss) {
      bf16x8 af0 = cvt8(xr[0][ss][0], xr[0][ss][1]);
      bf16x8 af1 = cvt8(xr[1][ss][0], xr[1][ss][1]);
#pragma unroll
      for (int j = 0; j < 3; ++j) {
        bf16x8 wfr = *(const bf16x8*)&wbuf[ci0 + j][ss][lane][0];
        acc[0][j] = __builtin_amdgcn_mfma_f32_16x16x32_bf16(af0, wfr, acc[0][j], 0, 0, 0);
        acc[1][j] = __builtin_amdgcn_mfma_f32_16x16x32_bf16(af1, wfr, acc[1][j], 0, 0, 0);
      }
    }
    __syncthreads();  // all reads done before next step's copies overwrite
  }

  // epilogue: C/D col=l16, row=quad*4+r
#pragma unroll
  for (int st = 0; st < 2; ++st) {
#pragma unroll
    for (int j = 0; j < 3; ++j) {
      const int ci = ci0 + j;
#pragma unroll
      for (int r = 0; r < 4; ++r) {
        int row = R0 + st * 16 + quad * 4 + r;
        unsigned short hv = f32_to_bf16(acc[st][j][r]);
        if (ci < 4) {
          qb[(size_t)row * 64 + ci * 16 + l16] = hv;
        } else if (ci < 8) {
          kb[(size_t)row * 64 + (ci - 4) * 16 + l16] = hv;
        } else {
          int b = row >> 12, tt = row & 4095;
          vt[((size_t)b * 80 + (ci - 8) * 16 + l16) * TSEQ + tt] = hv;
        }
      }
    }
  }
}

// ---- kernel 3: windowed causal attention, 4 waves per q-tile (32 keys each) ---
// Analytic shift slope*row => partials linear: O = sum O_h, l = sum l_h.
__global__ __launch_bounds__(256, 4) void attn_kernel(
    const unsigned short* __restrict__ qb, const unsigned short* __restrict__ kb,
    const unsigned short* __restrict__ vt, float* __restrict__ out) {
  __shared__ unsigned short pbuf[4][16][40];  // 16 q x 32 keys (+pad)
  __shared__ float obuf[4][5][16][17];        // partial O (+l in [4])

  const int lane = threadIdx.x & 63;
  const int wave = threadIdx.x >> 6;  // key-quarter
  const int l16 = lane & 15, quad = lane >> 4;
  const int tid = blockIdx.x;  // q-tile 0..1023
  const int b = tid & 3;
  const int r0 = (tid >> 2) << 4;
  const int j0 = (r0 > 112) ? (r0 - 112) : 0;
  const int jb = j0 + wave * 32;

  const unsigned short* kbase = kb + (size_t)b * TSEQ * 64;
  const unsigned short* vbase = vt + (size_t)b * 80 * TSEQ;

  const unsigned short* qrow = qb + (size_t)(b * TSEQ + r0 + l16) * 64 + quad * 8;
  bf16x8 qa0 = *(const bf16x8*)qrow;
  bf16x8 qa1 = *(const bf16x8*)(qrow + 32);

  f32x4 o[5];
#pragma unroll
  for (int dt = 0; dt < 5; ++dt) o[dt] = (f32x4){0.f, 0.f, 0.f, 0.f};

  const int irel = jb + l16 - r0 - quad * 4;  // key - query at nt=0,r=0
  const float fb = SL2E * (float)irel;

#pragma unroll
  for (int nt = 0; nt < 2; ++nt) {
    const unsigned short* krow = kbase + (size_t)(jb + nt * 16 + l16) * 64 + quad * 8;
    f32x4 sa = (f32x4){0.f, 0.f, 0.f, 0.f};
    sa = __builtin_amdgcn_mfma_f32_16x16x32_bf16(qa0, *(const bf16x8*)krow, sa, 0, 0, 0);
    sa = __builtin_amdgcn_mfma_f32_16x16x32_bf16(qa1, *(const bf16x8*)(krow + 32), sa, 0, 0, 0);
#pragma unroll
    for (int r = 0; r < 4; ++r) {
      float arg = fmaf(sa[r], LOG2E, fb + SL2E * (float)(nt * 16 - r));
      float p = exp2f(arg);
      if (irel + nt * 16 - r > 0) p = 0.f;  // causal
      pbuf[wave][quad * 4 + r][nt * 16 + l16] = f32_to_bf16(p);
    }
  }
  // same-wave DS write->read is in-order (validated R1-R6)
  bf16x8 pa = *(const bf16x8*)&pbuf[wave][l16][quad * 8];

#pragma unroll
  for (int dt = 0; dt < 5; ++dt) {  // dt=4: ones rows -> l = sum(p)
    const unsigned short* vrow = vbase + (size_t)(dt * 16 + l16) * TSEQ + jb + quad * 8;
    o[dt] = __builtin_amdgcn_mfma_f32_16x16x32_bf16(pa, *(const bf16x8*)vrow, o[dt], 0, 0, 0);
  }

#pragma unroll
  for (int dt = 0; dt < 5; ++dt)
#pragma unroll
    for (int r = 0; r < 4; ++r)
      obuf[wave][dt][quad * 4 + r][l16] = o[dt][r];

  __syncthreads();

  // combine 4 quarters: 16 rows x 64 cols, 4 floats/thread
  const int rr = threadIdx.x >> 4;
  const int c0 = (threadIdx.x & 15) * 4;
  const int dt = c0 >> 4, cc = c0 & 15;
  float l = obuf[0][4][rr][0] + obuf[1][4][rr][0] + obuf[2][4][rr][0] + obuf[3][4][rr][0];
  float invl = 1.0f / l;
  f32x4 res;
#pragma unroll
  for (int i = 0; i < 4; ++i)
    res[i] = (obuf[0][dt][rr][cc + i] + obuf[1][dt][rr][cc + i] +
              obuf[2][dt][rr][cc + i] + obuf[3][dt][rr][cc + i]) * invl;
  *(f32x4*)(out + (size_t)(b * TSEQ + r0 + rr) * 64 + c0) = res;
}

extern "C" void kernel_launch(void* const* d_in, const int* in_sizes, int n_in,
                              void* d_out, int out_size, void* d_ws, size_t ws_size,
                              hipStream_t stream) {
  const float* x  = (const float*)d_in[0];
  const float* wq = (const float*)d_in[1];
  const float* wk = (const float*)d_in[2];
  const float* wv = (const float*)d_in[3];
  float* out = (float*)d_out;

  // ws: Wb 384K | qb 2M | kb 2M | vt 2.62M (80 rows: 64 V + 16 ones)
  char* ws = (char*)d_ws;
  unsigned short* Wb = (unsigned short*)(ws);
  unsigned short* qb = (unsigned short*)(ws + 393216);
  unsigned short* kb = (unsigned short*)(ws + 393216 + 2097152);
  unsigned short* vt = (unsigned short*)(ws + 393216 + 2 * 2097152);

  init_kernel<<<512, 256, 0, stream>>>(wq, wk, wv, Wb, vt);
  proj_kernel<<<512, 256, 0, stream>>>(x, Wb, qb, kb, vt);
  attn_kernel<<<1024, 256, 0, stream>>>(qb, kb, vt, out);
}

// Round 8
// 123.968 us; speedup vs baseline: 1.1159x; 1.1159x over previous
//
#include <hip/hip_runtime.h>
#include <hip/hip_bf16.h>
#include <stdint.h>
#include <math.h>

typedef __attribute__((ext_vector_type(8))) short bf16x8;
typedef __attribute__((ext_vector_type(4))) float f32x4;

#define TSEQ 4096
#define LOG2E 1.44269504088896340736f
#define SLOPE 0.70710678118654752440f
#define SL2E (SLOPE * LOG2E)

__device__ __forceinline__ unsigned short f32_to_bf16(float f) {
  union { float f; unsigned int u; } v; v.f = f;
  unsigned int r = v.u + 0x7fffu + ((v.u >> 16) & 1u);
  return (unsigned short)(r >> 16);
}

__device__ __forceinline__ unsigned int pk2(float a, float b) {
  union { __hip_bfloat162 h; unsigned int u; } c;
  c.h = __float22bfloat162_rn(make_float2(a, b));  // v_cvt_pk_bf16_f32
  return c.u;
}
__device__ __forceinline__ bf16x8 cvt8(f32x4 a, f32x4 b) {
  union { unsigned int u[4]; bf16x8 v; } r;
  r.u[0] = pk2(a[0], a[1]); r.u[1] = pk2(a[2], a[3]);
  r.u[2] = pk2(b[0], b[1]); r.u[3] = pk2(b[2], b[3]);
  return r.v;
}

// async global->LDS, 16B/lane; dest = wave-uniform base + lane*16 (verified R3/R6)
__device__ __forceinline__ void async_cp16(const void* g, void* l) {
  __builtin_amdgcn_global_load_lds(
      (const __attribute__((address_space(1))) unsigned int*)g,
      (__attribute__((address_space(3))) unsigned int*)l, 16, 0, 0);
}

// ---- kernel 1: W fp32 -> FRAGMENT-MAJOR bf16 (q pre-scaled 1/32) + vt ones ----
// Wb frag(ci,s,lane)[j] = W[n=(ci&3)*16+(lane&15)][k=s*32+(lane>>4)*8+j],
// ci = coltile 0..11 (q:0-3,k:4-7,v:8-11), at offset ((ci*32+s)*64+lane)*8.
__global__ __launch_bounds__(256) void init_kernel(
    const float* __restrict__ wq, const float* __restrict__ wk,
    const float* __restrict__ wv, unsigned short* __restrict__ Wb,
    unsigned short* __restrict__ vt) {
  int tid = blockIdx.x * 256 + threadIdx.x;  // 0..131071
  if (tid < 24576) {
    int lane = tid & 63, s = (tid >> 6) & 31, nt = (tid >> 11) & 3, t = tid >> 13;
    int n = nt * 16 + (lane & 15);
    int k = s * 32 + (lane >> 4) * 8;
    const float* src = (t == 0 ? wq : (t == 1 ? wk : wv)) + (size_t)n * 1024 + k;
    f32x4 a = *(const f32x4*)src;
    f32x4 b = *(const f32x4*)(src + 4);
    if (t == 0) {
#pragma unroll
      for (int j = 0; j < 4; ++j) { a[j] *= 0.03125f; b[j] *= 0.03125f; }
    }
    *(bf16x8*)(Wb + (size_t)tid * 8) = cvt8(a, b);
  }
  // vt ones rows (dims 64..79), vt layout [4][80][4096]
  int b2 = tid >> 15, off = (tid & 32767) * 2;
  *(unsigned int*)(vt + (size_t)b2 * 327680 + 262144 + off) = 0x3F803F80u;
}

// ---- kernel 2: qkv projection, all-DMA, W amortized over 64 rows, dbuf -------
// 256 blocks x 256 thr; block = 64 rows x 192 cols; 16 steps of K=64.
// Staged bytes/block = 384K W + 256K x = 640 KB (vs R6's 512K over 32 rows).
// Double-buffered LDS (80 KB, 2 blocks/CU): DMA(step+1) issued before
// compute(step); single barrier per step drains it AFTER compute (overlap).
__global__ __launch_bounds__(256, 2) void proj_kernel(
    const float* __restrict__ x, const unsigned short* __restrict__ Wb,
    unsigned short* __restrict__ qb, unsigned short* __restrict__ kb,
    unsigned short* __restrict__ vt) {
  __shared__ float xbuf[2][64][64];                 // 2 x 16 KB, XOR-swizzled 16B slots
  __shared__ unsigned short wbuf[2][12][2][64][8];  // 2 x 24 KB, frag-major

  const int lane = threadIdx.x & 63;
  const int wave = threadIdx.x >> 6;
  const int l16 = lane & 15, quad = lane >> 4;
  const int R0 = blockIdx.x * 64;

  f32x4 acc[12];
#pragma unroll
  for (int i = 0; i < 12; ++i) acc[i] = (f32x4){0.f, 0.f, 0.f, 0.f};

  // x staging: copy c (c=wave*4+i) = rows c*4..c*4+3 (wave stages its own rows
  // wave*16..wave*16+15). lane -> row c*4+quad, slot l16 holds chunk l16^(row&15).
  const float* xsrc[4];
#pragma unroll
  for (int i = 0; i < 4; ++i) {
    int row = wave * 16 + i * 4 + quad;
    int g = l16 ^ (row & 15);
    xsrc[i] = x + (size_t)(R0 + row) * 1024 + g * 4;
  }
  // W staging: copy q (q=wave*6+j): ci=q>>1, ss=q&1, 1KB frag-major each
  const unsigned short* wsrc[6];
#pragma unroll
  for (int j = 0; j < 6; ++j) {
    int q = wave * 6 + j;
    wsrc[j] = Wb + ((size_t)((q >> 1) * 32 + (q & 1)) * 64 + lane) * 8;
  }

  // prologue: stage step 0 into buf 0
#pragma unroll
  for (int i = 0; i < 4; ++i)
    async_cp16(xsrc[i], &xbuf[0][wave * 16 + i * 4][0]);
#pragma unroll
  for (int j = 0; j < 6; ++j) {
    int q = wave * 6 + j;
    async_cp16(wsrc[j], &wbuf[0][q >> 1][q & 1][0][0]);
  }
  __syncthreads();

#pragma unroll 1
  for (int step = 0; step < 16; ++step) {
    const int cur = step & 1;
    if (step + 1 < 16) {  // issue next-step DMA first; drained at the barrier
      const int nxt = 1 - cur;
#pragma unroll
      for (int i = 0; i < 4; ++i)
        async_cp16(xsrc[i] + (step + 1) * 64, &xbuf[nxt][wave * 16 + i * 4][0]);
#pragma unroll
      for (int j = 0; j < 6; ++j) {
        int q = wave * 6 + j;
        async_cp16(wsrc[j] + (size_t)(step + 1) * 2 * 64 * 8,
                   &wbuf[nxt][q >> 1][q & 1][0][0]);
      }
    }
    // compute on current buffer: wave = rows wave*16..+15, all 12 coltiles
#pragma unroll
    for (int ss = 0; ss < 2; ++ss) {
      const float* base = &xbuf[cur][wave * 16 + l16][0];
      f32x4 a0 = *(const f32x4*)(base + ((ss * 8 + quad * 2) ^ l16) * 4);
      f32x4 a1 = *(const f32x4*)(base + ((ss * 8 + quad * 2 + 1) ^ l16) * 4);
      bf16x8 af = cvt8(a0, a1);
#pragma unroll
      for (int ci = 0; ci < 12; ++ci) {
        bf16x8 wfr = *(const bf16x8*)&wbuf[cur][ci][ss][lane][0];
        acc[ci] = __builtin_amdgcn_mfma_f32_16x16x32_bf16(af, wfr, acc[ci], 0, 0, 0);
      }
    }
    __syncthreads();  // drains next-step DMA (post-compute) + joins waves
  }

  // epilogue: C/D col=l16, row=quad*4+r
#pragma unroll
  for (int ci = 0; ci < 12; ++ci) {
#pragma unroll
    for (int r = 0; r < 4; ++r) {
      int row = R0 + wave * 16 + quad * 4 + r;
      unsigned short hv = f32_to_bf16(acc[ci][r]);
      if (ci < 4) {
        qb[(size_t)row * 64 + ci * 16 + l16] = hv;
      } else if (ci < 8) {
        kb[(size_t)row * 64 + (ci - 4) * 16 + l16] = hv;
      } else {
        int b = row >> 12, tt = row & 4095;
        vt[((size_t)b * 80 + (ci - 8) * 16 + l16) * TSEQ + tt] = hv;
      }
    }
  }
}

// ---- kernel 3: windowed causal attention, 4 waves per q-tile (32 keys each) ---
// Analytic shift slope*row => partials linear: O = sum O_h, l = sum l_h.
__global__ __launch_bounds__(256, 4) void attn_kernel(
    const unsigned short* __restrict__ qb, const unsigned short* __restrict__ kb,
    const unsigned short* __restrict__ vt, float* __restrict__ out) {
  __shared__ unsigned short pbuf[4][16][40];  // 16 q x 32 keys (+pad)
  __shared__ float obuf[4][5][16][17];        // partial O (+l in [4])

  const int lane = threadIdx.x & 63;
  const int wave = threadIdx.x >> 6;  // key-quarter
  const int l16 = lane & 15, quad = lane >> 4;
  const int tid = blockIdx.x;  // q-tile 0..1023
  const int b = tid & 3;
  const int r0 = (tid >> 2) << 4;
  const int j0 = (r0 > 112) ? (r0 - 112) : 0;
  const int jb = j0 + wave * 32;

  const unsigned short* kbase = kb + (size_t)b * TSEQ * 64;
  const unsigned short* vbase = vt + (size_t)b * 80 * TSEQ;

  const unsigned short* qrow = qb + (size_t)(b * TSEQ + r0 + l16) * 64 + quad * 8;
  bf16x8 qa0 = *(const bf16x8*)qrow;
  bf16x8 qa1 = *(const bf16x8*)(qrow + 32);

  f32x4 o[5];
#pragma unroll
  for (int dt = 0; dt < 5; ++dt) o[dt] = (f32x4){0.f, 0.f, 0.f, 0.f};

  const int irel = jb + l16 - r0 - quad * 4;  // key - query at nt=0,r=0
  const float fb = SL2E * (float)irel;

#pragma unroll
  for (int nt = 0; nt < 2; ++nt) {
    const unsigned short* krow = kbase + (size_t)(jb + nt * 16 + l16) * 64 + quad * 8;
    f32x4 sa = (f32x4){0.f, 0.f, 0.f, 0.f};
    sa = __builtin_amdgcn_mfma_f32_16x16x32_bf16(qa0, *(const bf16x8*)krow, sa, 0, 0, 0);
    sa = __builtin_amdgcn_mfma_f32_16x16x32_bf16(qa1, *(const bf16x8*)(krow + 32), sa, 0, 0, 0);
#pragma unroll
    for (int r = 0; r < 4; ++r) {
      float arg = fmaf(sa[r], LOG2E, fb + SL2E * (float)(nt * 16 - r));
      float p = exp2f(arg);
      if (irel + nt * 16 - r > 0) p = 0.f;  // causal
      pbuf[wave][quad * 4 + r][nt * 16 + l16] = f32_to_bf16(p);
    }
  }
  // same-wave DS write->read is in-order (validated R1-R7)
  bf16x8 pa = *(const bf16x8*)&pbuf[wave][l16][quad * 8];

#pragma unroll
  for (int dt = 0; dt < 5; ++dt) {  // dt=4: ones rows -> l = sum(p)
    const unsigned short* vrow = vbase + (size_t)(dt * 16 + l16) * TSEQ + jb + quad * 8;
    o[dt] = __builtin_amdgcn_mfma_f32_16x16x32_bf16(pa, *(const bf16x8*)vrow, o[dt], 0, 0, 0);
  }

#pragma unroll
  for (int dt = 0; dt < 5; ++dt)
#pragma unroll
    for (int r = 0; r < 4; ++r)
      obuf[wave][dt][quad * 4 + r][l16] = o[dt][r];

  __syncthreads();

  // combine 4 quarters: 16 rows x 64 cols, 4 floats/thread
  const int rr = threadIdx.x >> 4;
  const int c0 = (threadIdx.x & 15) * 4;
  const int dt = c0 >> 4, cc = c0 & 15;
  float l = obuf[0][4][rr][0] + obuf[1][4][rr][0] + obuf[2][4][rr][0] + obuf[3][4][rr][0];
  float invl = 1.0f / l;
  f32x4 res;
#pragma unroll
  for (int i = 0; i < 4; ++i)
    res[i] = (obuf[0][dt][rr][cc + i] + obuf[1][dt][rr][cc + i] +
              obuf[2][dt][rr][cc + i] + obuf[3][dt][rr][cc + i]) * invl;
  *(f32x4*)(out + (size_t)(b * TSEQ + r0 + rr) * 64 + c0) = res;
}

extern "C" void kernel_launch(void* const* d_in, const int* in_sizes, int n_in,
                              void* d_out, int out_size, void* d_ws, size_t ws_size,
                              hipStream_t stream) {
  const float* x  = (const float*)d_in[0];
  const float* wq = (const float*)d_in[1];
  const float* wk = (const float*)d_in[2];
  const float* wv = (const float*)d_in[3];
  float* out = (float*)d_out;

  // ws: Wb 384K | qb 2M | kb 2M | vt 2.62M (80 rows: 64 V + 16 ones)
  char* ws = (char*)d_ws;
  unsigned short* Wb = (unsigned short*)(ws);
  unsigned short* qb = (unsigned short*)(ws + 393216);
  unsigned short* kb = (unsigned short*)(ws + 393216 + 2097152);
  unsigned short* vt = (unsigned short*)(ws + 393216 + 2 * 2097152);

  init_kernel<<<512, 256, 0, stream>>>(wq, wk, wv, Wb, vt);
  proj_kernel<<<256, 256, 0, stream>>>(x, Wb, qb, kb, vt);
  attn_kernel<<<1024, 256, 0, stream>>>(qb, kb, vt, out);
}